// Round 4
// baseline (808.435 us; speedup 1.0000x reference)
//
#include <hip/hip_runtime.h>
#include <hip/hip_bf16.h>

typedef unsigned short u16;
typedef unsigned int   u32;
typedef __bf16 bf16x8 __attribute__((ext_vector_type(8)));
typedef float  f32x4  __attribute__((ext_vector_type(4)));

#define SEQ   2304
#define DM    3072
#define NH    24
#define HD    128
#define S_TXT 256
#define S_IMG 2048
#define SCALE 0.08838834764831845f  // 1/sqrt(128)

__device__ __forceinline__ u16 f2bf(float x) {  // RNE fp32->bf16
  u32 u = __float_as_uint(x);
  u += 0x7fffu + ((u >> 16) & 1u);
  return (u16)(u >> 16);
}
__device__ __forceinline__ float bf2f(u16 b) {
  return __uint_as_float(((u32)b) << 16);
}
__device__ __forceinline__ f32x4 zero4() { f32x4 z = {0.f, 0.f, 0.f, 0.f}; return z; }
__device__ __forceinline__ u32 cvtpk(float lo, float hi) {
  u32 r;
  asm("v_cvt_pk_bf16_f32 %0, %1, %2" : "=v"(r) : "v"(lo), "v"(hi));
  return r;
}

// async global->LDS, 16B/lane; LDS dest is wave-uniform base + lane*16 (linear).
#define GLDS16(gp, lp) __builtin_amdgcn_global_load_lds( \
    (__attribute__((address_space(1))) void*)(gp),       \
    (__attribute__((address_space(3))) void*)(lp), 16, 0, 0)

// ---------------- fp32 -> bf16 elementwise ----------------
__global__ __launch_bounds__(256) void conv_bf16_k(const float* __restrict__ src,
                                                   u16* __restrict__ dst, int n4) {
  int i = blockIdx.x * 256 + threadIdx.x;
  if (i >= n4) return;
  float4 v = ((const float4*)src)[i];
  ushort4 o;
  o.x = f2bf(v.x); o.y = f2bf(v.y); o.z = f2bf(v.z); o.w = f2bf(v.w);
  ((ushort4*)dst)[i] = o;
}

// ---------------- weight fp32 [K][N] -> bf16 [N][K] (transpose), 64x64 tiles ----------------
struct WP { const float* s[8]; u16* d[8]; };

__global__ __launch_bounds__(256) void w_transpose_k(WP p) {
  __shared__ float tile[64][65];   // pad 65: transpose-read 2-way (free) banks
  const float* __restrict__ src = p.s[blockIdx.z];
  u16* __restrict__ dst = p.d[blockIdx.z];
  const int c0 = blockIdx.x * 64, r0 = blockIdx.y * 64;
  const int tr = threadIdx.x >> 4;   // 0..15
  const int tc = threadIdx.x & 15;   // 0..15
#pragma unroll
  for (int i = 0; i < 4; ++i) {
    float4 v = *(const float4*)&src[(size_t)(r0 + i*16 + tr) * DM + c0 + tc*4];
    tile[i*16 + tr][tc*4 + 0] = v.x;
    tile[i*16 + tr][tc*4 + 1] = v.y;
    tile[i*16 + tr][tc*4 + 2] = v.z;
    tile[i*16 + tr][tc*4 + 3] = v.w;
  }
  __syncthreads();
#pragma unroll
  for (int j = 0; j < 4; ++j) {
    const int nloc = j*16 + tr;
    const int kloc = tc*4;
    ushort4 o;
    o.x = f2bf(tile[kloc + 0][nloc]);
    o.y = f2bf(tile[kloc + 1][nloc]);
    o.z = f2bf(tile[kloc + 2][nloc]);
    o.w = f2bf(tile[kloc + 3][nloc]);
    *(ushort4*)&dst[(size_t)(c0 + nloc) * DM + r0 + kloc] = o;
  }
}

// ---------------- merged GEMM + fused epilogues ----------------
// 1D grid, bijective XCD-chunked swizzle (nwg % 8 == 0), decode bm fastest.
// mode 0 (QKV): bz 0/1 -> fused RMSNorm+RoPE (+1/sqrt(128) on Q), bf16
//   head-split [24][2304][128]; bz 2 -> V written transposed [24][128][2304].
// mode 1 (out-proj): fp32 + bias, enc/img row remap into d_out.
struct GArgs {
  const u16* A;
  const u16* Bimg0; const u16* Bimg1; const u16* Bimg2;
  const u16* Benc0; const u16* Benc1; const u16* Benc2;
  const float* bEnc0; const float* bEnc1; const float* bEnc2;
  const float* bImg;
  const float* cosT; const float* sinT;
  const float* nq; const float* nk; const float* naq; const float* nak;
  void* out0; void* out1; void* out2;
  int mode;
};

__global__ __launch_bounds__(256) void gemm_bt_k(GArgs p) {
  __shared__ __attribute__((aligned(128))) char As[128*128];
  __shared__ __attribute__((aligned(128))) char Bs[128*128];
  // XCD-chunked bijective swizzle
  const int chunk = gridDim.x >> 3;
  const int wg = (blockIdx.x & 7) * chunk + (blockIdx.x >> 3);
  const int bm = wg % 18;
  const int bt = wg / 18;
  const int bn = bt % 24;
  const int bz = bt / 24;
  const bool enc = (bm < 2);
  const u16* __restrict__ Bm = (bz == 0) ? (enc ? p.Benc0 : p.Bimg0)
                             : (bz == 1) ? (enc ? p.Benc1 : p.Bimg1)
                                         : (enc ? p.Benc2 : p.Bimg2);
  const float* __restrict__ bias = enc ? ((bz == 0) ? p.bEnc0 : (bz == 1) ? p.bEnc1 : p.bEnc2)
                                       : p.bImg;
  void* out = (bz == 0) ? p.out0 : (bz == 1) ? p.out1 : p.out2;
  const int tid = threadIdx.x;
  const int w = tid >> 6, l = tid & 63;
  const int wr = w >> 1, wc = w & 1;
  const int g = l >> 4, q16 = l & 15;

  f32x4 acc[4][4];
#pragma unroll
  for (int mi = 0; mi < 4; ++mi)
#pragma unroll
    for (int ni = 0; ni < 4; ++ni) acc[mi][ni] = zero4();

  const int srow  = l >> 3;
  const int scolb = ((l & 7) ^ srow) << 4;
  const char* Ag = (const char*)(p.A + (size_t)(bm*128 + w*32) * DM) + (size_t)srow * (DM*2) + scolb;
  const char* Bg = (const char*)(Bm  + (size_t)(bn*128 + w*32) * DM) + (size_t)srow * (DM*2) + scolb;
  char* AsW = As + (w*32) * 128;
  char* BsW = Bs + (w*32) * 128;

  for (int kt = 0; kt < DM/64; ++kt) {
#pragma unroll
    for (int i = 0; i < 4; ++i) {
      GLDS16(Ag + (size_t)i*8*(DM*2) + kt*128, AsW + i*8*128);
      GLDS16(Bg + (size_t)i*8*(DM*2) + kt*128, BsW + i*8*128);
    }
    __syncthreads();
#pragma unroll
    for (int kk = 0; kk < 2; ++kk) {
      bf16x8 af[4], bfr[4];
#pragma unroll
      for (int mi = 0; mi < 4; ++mi) {
        const int row = wr*64 + mi*16 + q16;
        const int cb  = ((kk << 6) + (g << 4)) ^ ((row & 7) << 4);
        af[mi] = *(const bf16x8*)(As + row*128 + cb);
      }
#pragma unroll
      for (int ni = 0; ni < 4; ++ni) {
        const int row = wc*64 + ni*16 + q16;
        const int cb  = ((kk << 6) + (g << 4)) ^ ((row & 7) << 4);
        bfr[ni] = *(const bf16x8*)(Bs + row*128 + cb);
      }
#pragma unroll
      for (int mi = 0; mi < 4; ++mi)
#pragma unroll
        for (int ni = 0; ni < 4; ++ni)
          acc[mi][ni] = __builtin_amdgcn_mfma_f32_16x16x32_bf16(af[mi], bfr[ni], acc[mi][ni], 0, 0, 0);
    }
    __syncthreads();
  }

  if (p.mode == 0) {
    // encoder bias (block-uniform predicate)
    if (bias) {
#pragma unroll
      for (int ni = 0; ni < 4; ++ni) {
        const float bv = bias[bn*128 + wc*64 + ni*16 + q16];
#pragma unroll
        for (int mi = 0; mi < 4; ++mi) {
          f32x4 t = acc[mi][ni];
#pragma unroll
          for (int r = 0; r < 4; ++r) t[r] += bv;
          acc[mi][ni] = t;
        }
      }
    }
    if (bz == 2) {
      // V: write transposed [head][d][token]
      u16* Vt_ = (u16*)out;
#pragma unroll
      for (int mi = 0; mi < 4; ++mi) {
        const int tb = bm*128 + wr*64 + mi*16 + g*4;
#pragma unroll
        for (int ni = 0; ni < 4; ++ni) {
          const int col = wc*64 + ni*16 + q16;
          ushort4 o4;
          o4.x = f2bf(acc[mi][ni][0]); o4.y = f2bf(acc[mi][ni][1]);
          o4.z = f2bf(acc[mi][ni][2]); o4.w = f2bf(acc[mi][ni][3]);
          *(ushort4*)&Vt_[((size_t)bn*HD + col)*SEQ + tb] = o4;
        }
      }
    } else {
      // Q/K: fused RMSNorm + RoPE (+ Q pre-scale). Tile spans the full head dim.
      float ss[4][4];
#pragma unroll
      for (int mi = 0; mi < 4; ++mi)
#pragma unroll
        for (int r = 0; r < 4; ++r) {
          float v = 0.f;
#pragma unroll
          for (int ni = 0; ni < 4; ++ni) v += acc[mi][ni][r] * acc[mi][ni][r];
#pragma unroll
          for (int msk = 1; msk < 16; msk <<= 1) v += __shfl_xor(v, msk, 64);
          ss[mi][r] = v;
        }
      float* red = (float*)As;  // LDS free after final barrier
      if (q16 == 0) {
#pragma unroll
        for (int mi = 0; mi < 4; ++mi)
#pragma unroll
          for (int r = 0; r < 4; ++r)
            red[w*64 + mi*16 + g*4 + r] = ss[mi][r];
      }
      __syncthreads();
      const float* nw = (bz == 0) ? (enc ? p.naq : p.nq) : (enc ? p.nak : p.nk);
      u16* O_ = (u16*)out;
#pragma unroll
      for (int mi = 0; mi < 4; ++mi)
#pragma unroll
        for (int r = 0; r < 4; ++r) {
          const float tot = ss[mi][r] + red[(w^1)*64 + mi*16 + g*4 + r];
          const float rr = rsqrtf(tot * (1.0f/128.0f) + 1e-6f);
          const int t = bm*128 + wr*64 + mi*16 + g*4 + r;
#pragma unroll
          for (int ni = 0; ni < 4; ++ni) {
            const int col = wc*64 + ni*16 + q16;
            const float xn = acc[mi][ni][r] * rr * nw[col];
            const float pt = __shfl_xor(xn, 1, 64);
            const float c  = p.cosT[(size_t)t*HD + col];
            const float sn = p.sinT[(size_t)t*HD + col];
            float o = (q16 & 1) ? (xn*c + pt*sn) : (xn*c - pt*sn);
            if (bz == 0) o *= SCALE;
            O_[((size_t)bn*SEQ + t)*HD + col] = f2bf(o);
          }
        }
    }
  } else {
    // out-proj: fp32 + bias, enc/img row remap
#pragma unroll
    for (int mi = 0; mi < 4; ++mi) {
      const int mbase = bm*128 + wr*64 + mi*16 + g*4;
#pragma unroll
      for (int ni = 0; ni < 4; ++ni) {
        const int ncol = bn*128 + wc*64 + ni*16 + q16;
        const float bv = bias ? bias[ncol] : 0.f;
#pragma unroll
        for (int r = 0; r < 4; ++r) {
          const int row = mbase + r;
          const size_t orow = (row < S_TXT) ? (size_t)(S_IMG + row) : (size_t)(row - S_TXT);
          ((float*)out)[orow * DM + ncol] = acc[mi][ni][r] + bv;
        }
      }
    }
  }
}

// ---------------- flash attention (unchanged from R3: dbuf 2-phase, counted vmcnt) ----------------
__global__ __launch_bounds__(256) void attn_k(
    const u16* __restrict__ Q, const u16* __restrict__ K,
    const u16* __restrict__ Vt, u16* __restrict__ O) {
  __shared__ __attribute__((aligned(128))) char Kl[2][64*256];
  __shared__ __attribute__((aligned(128))) char Vl[2][128*128];
  __shared__ __attribute__((aligned(128))) char Pl[4][2048];
  const int orig = blockIdx.x;
  const int lin = (orig & 7) * 54 + (orig >> 3);   // bijective: 432 = 8*54
  const int h = lin / 18, qb = lin % 18;
  const int tid = threadIdx.x, w = tid >> 6, l = tid & 63;
  const int g = l >> 4, q16 = l & 15;
  const int NT = SEQ / 64;

  const u16* Qh = Q  + ((size_t)h * SEQ + qb*128 + w*32) * HD;
  const u16* Kh = K  + (size_t)h * SEQ * HD;
  const u16* Vh = Vt + (size_t)h * HD * SEQ;

  bf16x8 qf[2][4];
#pragma unroll
  for (int qt = 0; qt < 2; ++qt)
#pragma unroll
    for (int kf = 0; kf < 4; ++kf)
      qf[qt][kf] = *(const bf16x8*)(Qh + (qt*16 + q16) * HD + kf*32 + g*8);

  f32x4 o[2][8];
#pragma unroll
  for (int qt = 0; qt < 2; ++qt)
#pragma unroll
    for (int db = 0; db < 8; ++db) o[qt][db] = zero4();
  float m[2]  = {-3e38f, -3e38f};
  float rl[2] = {0.f, 0.f};

  const int vswz = ((l & 7) ^ (l >> 3)) << 4;
  const int pswz = (q16 & 7) << 4;

  auto STAGE = [&](int buf, int kb) {
#pragma unroll
    for (int i = 0; i < 4; ++i) {
      const int rloc = i*4 + (l >> 4);
      const int colb = ((l & 15) << 4) ^ ((rloc & 7) << 4);
      GLDS16((const char*)Kh + ((size_t)(kb*64 + w*16 + rloc)) * 256 + colb,
             &Kl[buf][(w*16 + i*4) * 256]);
    }
#pragma unroll
    for (int i = 0; i < 4; ++i) {
      const int rloc = w*32 + i*8 + (l >> 3);
      GLDS16((const char*)Vh + (size_t)rloc * (SEQ*2) + kb*128 + vswz,
             &Vl[buf][(w*32 + i*8) * 128]);
    }
  };

  STAGE(0, 0);
  int cur = 0;

  for (int kb = 0; kb < NT; ++kb) {
    if (kb + 1 < NT) {
      STAGE(cur ^ 1, kb + 1);
      asm volatile("s_waitcnt vmcnt(8)" ::: "memory");
    } else {
      asm volatile("s_waitcnt vmcnt(0)" ::: "memory");
    }
    __builtin_amdgcn_s_barrier();
    __builtin_amdgcn_sched_barrier(0);

    const char* Kb_ = Kl[cur];
    const char* Vb_ = Vl[cur];

    f32x4 s[2][4];
#pragma unroll
    for (int qt = 0; qt < 2; ++qt)
#pragma unroll
      for (int mi = 0; mi < 4; ++mi) s[qt][mi] = zero4();
    __builtin_amdgcn_s_setprio(1);
#pragma unroll
    for (int mi = 0; mi < 4; ++mi) {
      const int row = mi*16 + q16;
      bf16x8 kfr[4];
#pragma unroll
      for (int kf = 0; kf < 4; ++kf) {
        const int cb = ((kf << 6) + (g << 4)) ^ ((row & 7) << 4);
        kfr[kf] = *(const bf16x8*)(Kb_ + row*256 + cb);
      }
#pragma unroll
      for (int kf = 0; kf < 4; ++kf) {
        s[0][mi] = __builtin_amdgcn_mfma_f32_16x16x32_bf16(kfr[kf], qf[0][kf], s[0][mi], 0, 0, 0);
        s[1][mi] = __builtin_amdgcn_mfma_f32_16x16x32_bf16(kfr[kf], qf[1][kf], s[1][mi], 0, 0, 0);
      }
    }
    __builtin_amdgcn_s_setprio(0);

    float rsv[2];
    bf16x8 pa[2][2];
    char* Pw = Pl[w];
#pragma unroll
    for (int qt = 0; qt < 2; ++qt) {
      float mx = s[qt][0][0];
#pragma unroll
      for (int mi = 0; mi < 4; ++mi)
#pragma unroll
        for (int r = 0; r < 4; ++r) mx = fmaxf(mx, s[qt][mi][r]);
      mx = fmaxf(mx, __shfl_xor(mx, 16, 64));
      mx = fmaxf(mx, __shfl_xor(mx, 32, 64));
      const float mn = fmaxf(m[qt], mx);
      rsv[qt] = __expf(m[qt] - mn);
      m[qt] = mn;
      float sum = 0.f;
#pragma unroll
      for (int mi = 0; mi < 4; ++mi) {
        f32x4 t = s[qt][mi];
#pragma unroll
        for (int r = 0; r < 4; ++r) { t[r] = __expf(t[r] - mn); sum += t[r]; }
        s[qt][mi] = t;
      }
      sum += __shfl_xor(sum, 16, 64);
      sum += __shfl_xor(sum, 32, 64);
      rl[qt] = rl[qt] * rsv[qt] + sum;
#pragma unroll
      for (int mi = 0; mi < 4; ++mi) {
        uint2 pk;
        pk.x = cvtpk(s[qt][mi][0], s[qt][mi][1]);
        pk.y = cvtpk(s[qt][mi][2], s[qt][mi][3]);
        *(uint2*)(Pw + ((q16*128 + mi*32 + g*8) ^ pswz)) = pk;
      }
#pragma unroll
      for (int kblk = 0; kblk < 2; ++kblk)
        pa[qt][kblk] = *(const bf16x8*)(Pw + ((q16*128 + kblk*64 + g*16) ^ pswz));
    }

#pragma unroll
    for (int qt = 0; qt < 2; ++qt) {
      float rs4[4];
#pragma unroll
      for (int r = 0; r < 4; ++r)
        rs4[r] = __shfl(rsv[qt], (g << 4) + (g << 2) + r, 64);
#pragma unroll
      for (int db = 0; db < 8; ++db) {
        f32x4 t = o[qt][db];
#pragma unroll
        for (int r = 0; r < 4; ++r) t[r] *= rs4[r];
        o[qt][db] = t;
      }
    }

    __builtin_amdgcn_s_setprio(1);
#pragma unroll
    for (int kblk = 0; kblk < 2; ++kblk)
#pragma unroll
      for (int db = 0; db < 8; ++db) {
        const int vrow = db*16 + q16;
        const int vcb  = ((kblk << 6) + (g << 4)) ^ ((vrow & 7) << 4);
        bf16x8 vb = *(const bf16x8*)(Vb_ + vrow*128 + vcb);
        o[0][db] = __builtin_amdgcn_mfma_f32_16x16x32_bf16(pa[0][kblk], vb, o[0][db], 0, 0, 0);
        o[1][db] = __builtin_amdgcn_mfma_f32_16x16x32_bf16(pa[1][kblk], vb, o[1][db], 0, 0, 0);
      }
    __builtin_amdgcn_s_setprio(0);

    asm volatile("s_waitcnt lgkmcnt(0)" ::: "memory");
    __builtin_amdgcn_s_barrier();
    __builtin_amdgcn_sched_barrier(0);
    cur ^= 1;
  }

#pragma unroll
  for (int qt = 0; qt < 2; ++qt) {
    float inv4[4];
#pragma unroll
    for (int r = 0; r < 4; ++r)
      inv4[r] = 1.f / __shfl(rl[qt], (g << 4) + (g << 2) + r, 64);
#pragma unroll
    for (int db = 0; db < 8; ++db)
#pragma unroll
      for (int r = 0; r < 4; ++r) {
        const int token = qb*128 + w*32 + qt*16 + g*4 + r;
        const int col = h*HD + db*16 + q16;
        O[(size_t)token * DM + col] = f2bf(o[qt][db][r] * inv4[r]);
      }
  }
}

// ---------------- host ----------------
extern "C" void kernel_launch(void* const* d_in, const int* in_sizes, int n_in,
                              void* d_out, int out_size, void* d_ws, size_t ws_size,
                              hipStream_t stream) {
  const float* hidden = (const float*)d_in[0];
  const float* ench   = (const float*)d_in[1];
  const float* cosT   = (const float*)d_in[2];
  const float* sinT   = (const float*)d_in[3];
  const float* wq  = (const float*)d_in[4];
  const float* wk  = (const float*)d_in[5];
  const float* wv  = (const float*)d_in[6];
  const float* wqa = (const float*)d_in[7];
  const float* wka = (const float*)d_in[8];
  const float* wva = (const float*)d_in[9];
  const float* bqa = (const float*)d_in[10];
  const float* bka = (const float*)d_in[11];
  const float* bva = (const float*)d_in[12];
  const float* nq  = (const float*)d_in[13];
  const float* nk  = (const float*)d_in[14];
  const float* naq = (const float*)d_in[15];
  const float* nak = (const float*)d_in[16];
  const float* w_out     = (const float*)d_in[17];
  const float* b_out     = (const float*)d_in[18];
  const float* w_add_out = (const float*)d_in[19];
  const float* b_add_out = (const float*)d_in[20];
  float* outp = (float*)d_out;
  (void)in_sizes; (void)n_in; (void)out_size; (void)ws_size;

  char* ws = (char*)d_ws;
  size_t off = 0;
  auto alloc = [&](size_t n) { char* p = ws + off; off += (n + 255) & ~(size_t)255; return p; };
  u16* wt[8];
  for (int i = 0; i < 8; ++i) wt[i] = (u16*)alloc((size_t)DM * DM * 2);
  u16* xb = (u16*)alloc((size_t)SEQ * DM * 2);   // enc rows [0,256) then img
  u16* Qb = (u16*)alloc((size_t)NH * SEQ * HD * 2);
  u16* Kb = (u16*)alloc((size_t)NH * SEQ * HD * 2);
  u16* Vt = (u16*)alloc((size_t)NH * HD * SEQ * 2);
  u16* Ob = (u16*)alloc((size_t)SEQ * DM * 2);

  conv_bf16_k<<<(S_TXT*DM/4)/256, 256, 0, stream>>>(ench, xb, S_TXT*DM/4);
  conv_bf16_k<<<(S_IMG*DM/4)/256, 256, 0, stream>>>(hidden, xb + (size_t)S_TXT*DM, S_IMG*DM/4);

  WP wp;
  wp.s[0] = wq;  wp.s[1] = wk;  wp.s[2] = wv;
  wp.s[3] = wqa; wp.s[4] = wka; wp.s[5] = wva;
  wp.s[6] = w_out; wp.s[7] = w_add_out;
  for (int i = 0; i < 8; ++i) wp.d[i] = wt[i];
  w_transpose_k<<<dim3(48, 48, 8), 256, 0, stream>>>(wp);

  // merged QKV projection + fused norm/rope/V-transpose epilogues
  GArgs qkv;
  qkv.A = xb;
  qkv.Bimg0 = wt[0]; qkv.Bimg1 = wt[1]; qkv.Bimg2 = wt[2];
  qkv.Benc0 = wt[3]; qkv.Benc1 = wt[4]; qkv.Benc2 = wt[5];
  qkv.bEnc0 = bqa;   qkv.bEnc1 = bka;   qkv.bEnc2 = bva;
  qkv.bImg  = nullptr;
  qkv.cosT = cosT; qkv.sinT = sinT;
  qkv.nq = nq; qkv.nk = nk; qkv.naq = naq; qkv.nak = nak;
  qkv.out0 = Qb; qkv.out1 = Kb; qkv.out2 = Vt;
  qkv.mode = 0;
  gemm_bt_k<<<1296, 256, 0, stream>>>(qkv);

  attn_k<<<432, 256, 0, stream>>>(Qb, Kb, Vt, Ob);

  // merged output projection
  GArgs op;
  op.A = Ob;
  op.Bimg0 = wt[6]; op.Bimg1 = wt[6]; op.Bimg2 = wt[6];
  op.Benc0 = wt[7]; op.Benc1 = wt[7]; op.Benc2 = wt[7];
  op.bEnc0 = b_add_out; op.bEnc1 = b_add_out; op.bEnc2 = b_add_out;
  op.bImg  = b_out;
  op.cosT = nullptr; op.sinT = nullptr;
  op.nq = nullptr; op.nk = nullptr; op.naq = nullptr; op.nak = nullptr;
  op.out0 = outp; op.out1 = outp; op.out2 = outp;
  op.mode = 1;
  gemm_bt_k<<<432, 256, 0, stream>>>(op);
}